// Round 1
// baseline (439.753 us; speedup 1.0000x reference)
//
#include <hip/hip_runtime.h>
#include <hip/hip_bf16.h>
#include <math.h>

#define BB 2
#define SS 2048
#define DD 1024
#define HH 16
#define HD 64
#define MM (BB*SS)          // 4096
#define NQKV 3072
#define LN_EPS 1e-5f

typedef unsigned short u16;
typedef __attribute__((ext_vector_type(8))) short short8;
typedef __attribute__((ext_vector_type(4))) float f32x4;
typedef __attribute__((ext_vector_type(4))) unsigned short u16x4;

__device__ __forceinline__ u16 f2bf(float f) {
    union { __hip_bfloat16 h; u16 u; } cv;
    cv.h = __float2bfloat16(f);
    return cv.u;
}

// ---------------- convert x (fp32 -> bf16), 4 elems/thread ----------------
__global__ void k_convert_x(const float* __restrict__ x, u16* __restrict__ xb) {
    int i = blockIdx.x * blockDim.x + threadIdx.x;      // 0..1M-1
    float4 v = ((const float4*)x)[i];
    u16x4 o;
    o[0] = f2bf(v.x); o[1] = f2bf(v.y); o[2] = f2bf(v.z); o[3] = f2bf(v.w);
    ((u16x4*)xb)[i] = o;
}

// ---------------- transpose + convert weights: Wt[n][k] = bf16(W[k][n]) ----
__global__ void k_transpose_w(const float* __restrict__ Wq, const float* __restrict__ Wk,
                              const float* __restrict__ Wv, const float* __restrict__ Wo,
                              u16* __restrict__ wqkvt, u16* __restrict__ wot) {
    __shared__ float t[32][33];
    int z = blockIdx.z;
    const float* W = (z == 0) ? Wq : (z == 1) ? Wk : (z == 2) ? Wv : Wo;
    u16* dst = (z < 3) ? (wqkvt + (size_t)z * DD * DD) : wot;
    int k0 = blockIdx.x * 32, n0 = blockIdx.y * 32;
    #pragma unroll
    for (int r = 0; r < 32; r += 8)
        t[threadIdx.y + r][threadIdx.x] = W[(size_t)(k0 + threadIdx.y + r) * DD + n0 + threadIdx.x];
    __syncthreads();
    #pragma unroll
    for (int r = 0; r < 32; r += 8)
        dst[(size_t)(n0 + threadIdx.y + r) * DD + k0 + threadIdx.x] = f2bf(t[threadIdx.x][threadIdx.y + r]);
}

// ---------------- RoPE tables: cos/sin[s][j] = cos/sin(s * invf[j%32]) -----
__global__ void k_rope_table(float* __restrict__ cosb, float* __restrict__ sinb) {
    int idx = blockIdx.x * blockDim.x + threadIdx.x;    // 0..131071
    int s = idx >> 6, j = idx & 63;
    double invf = pow(10000.0, -((double)(2 * (j & 31))) / 64.0);
    double ang = (double)s * invf;
    cosb[idx] = (float)cos(ang);
    sinb[idx] = (float)sin(ang);
}

// ---------------- QKV GEMM: [4096x1024] @ [1024x3072] + bias, RoPE epilogue
// A = xb (M x K, row-major), Bt = wqkvt (N x K, row-major). 128x128 tile, 4 waves.
__global__ __launch_bounds__(256) void k_gemm_qkv(
        const u16* __restrict__ xb, const u16* __restrict__ wqkvt,
        const float* __restrict__ bq, const float* __restrict__ bk, const float* __restrict__ bv,
        const float* __restrict__ cosb, const float* __restrict__ sinb,
        u16* __restrict__ q, u16* __restrict__ k, u16* __restrict__ vt) {
    int lane = threadIdx.x & 63, wid = threadIdx.x >> 6;
    int wm = wid >> 1, wn = wid & 1;
    int m0 = blockIdx.x * 128 + wm * 64;
    int n0 = blockIdx.y * 128 + wn * 64;
    int lr = lane & 15, lg = lane >> 4, lk = lg * 8;

    f32x4 acc[4][4] = {};
    for (int kk = 0; kk < DD; kk += 32) {
        short8 a[4], b[4];
        #pragma unroll
        for (int i = 0; i < 4; i++)
            a[i] = *(const short8*)(xb + (size_t)(m0 + i * 16 + lr) * DD + kk + lk);
        #pragma unroll
        for (int j = 0; j < 4; j++)
            b[j] = *(const short8*)(wqkvt + (size_t)(n0 + j * 16 + lr) * DD + kk + lk);
        #pragma unroll
        for (int i = 0; i < 4; i++)
            #pragma unroll
            for (int j = 0; j < 4; j++)
                acc[i][j] = __builtin_amdgcn_mfma_f32_16x16x32_bf16(a[i], b[j], acc[i][j], 0, 0, 0);
    }

    #pragma unroll
    for (int j = 0; j < 4; j++) {
        int n = n0 + j * 16 + lr;           // 0..3071
        int w = n >> 10;
        int n1 = n & 1023;
        int h = n1 >> 6, d = n1 & 63;
        float bias = (w == 0) ? bq[n1] : (w == 1) ? bk[n1] : bv[n1];
        #pragma unroll
        for (int i = 0; i < 4; i++) {
            #pragma unroll
            for (int r = 0; r < 4; r++) {
                int m = m0 + i * 16 + lg * 4 + r;
                int b_ = m >> 11, s = m & 2047;
                float val = acc[i][j][r] + bias;
                float part = __shfl_xor(val, 1);    // partner column d^1 (uniform exec)
                if (w < 2) {
                    float c = cosb[s * 64 + d], sn = sinb[s * 64 + d];
                    float rot = (d & 1) ? part : -part;   // rot[2i]=-t[2i+1], rot[2i+1]=t[2i]
                    val = val * c + rot * sn;
                }
                size_t bh = (size_t)(b_ * HH + h);
                if (w == 0) {
                    q[(bh * SS + s) * HD + d] = f2bf(val * 0.125f);   // fold 1/sqrt(64)
                } else if (w == 1) {
                    k[(bh * SS + s) * HD + d] = f2bf(val);
                } else {
                    vt[(bh * HD + d) * SS + s] = f2bf(val);           // V transposed (d-major)
                }
            }
        }
    }
}

// ---------------- Flash attention ------------------------------------------
// grid (S/64, B*H), 4 waves/block, each wave owns 16 q-rows. KV tile = 64.
#define PS 72   // padded LDS stride (keeps 16B alignment: 144B rows)
__global__ __launch_bounds__(256) void k_attn(
        const u16* __restrict__ q, const u16* __restrict__ kkv, const u16* __restrict__ vt,
        const float* __restrict__ cdr_bias, const float* __restrict__ cdr_w,
        u16* __restrict__ attnb) {
    __shared__ u16 plds[4][16][PS];
    int lane = threadIdx.x & 63, wid = threadIdx.x >> 6;
    int bh = blockIdx.y;
    int b_ = bh >> 4, h = bh & 15;
    int q0 = blockIdx.x * 64 + wid * 16;
    int lr = lane & 15, lg = lane >> 4, lk = lg * 8;
    float cw = cdr_w[0];

    const u16* qptr = q + ((size_t)bh * SS + q0 + lr) * HD + lk;
    short8 qa[2];
    qa[0] = *(const short8*)(qptr);
    qa[1] = *(const short8*)(qptr + 32);

    f32x4 acco[4] = {};
    float mrow[4] = {-1e30f, -1e30f, -1e30f, -1e30f};
    float lrow[4] = {0.f, 0.f, 0.f, 0.f};

    for (int kv0 = 0; kv0 < SS; kv0 += 64) {
        f32x4 accs[4] = {};
        #pragma unroll
        for (int n = 0; n < 4; n++) {
            const u16* kptr = kkv + ((size_t)bh * SS + kv0 + n * 16 + lr) * HD + lk;
            short8 kb0 = *(const short8*)(kptr);
            short8 kb1 = *(const short8*)(kptr + 32);
            accs[n] = __builtin_amdgcn_mfma_f32_16x16x32_bf16(qa[0], kb0, accs[n], 0, 0, 0);
            accs[n] = __builtin_amdgcn_mfma_f32_16x16x32_bf16(qa[1], kb1, accs[n], 0, 0, 0);
            float bias = cdr_bias[b_ * SS + kv0 + n * 16 + lr] * cw;
            #pragma unroll
            for (int r = 0; r < 4; r++) accs[n][r] += bias;
        }
        // online softmax per row (row = lg*4+r, 16 key-cols per lane-group, 4 n-subtiles)
        float alpha[4];
        #pragma unroll
        for (int r = 0; r < 4; r++) {
            float mx = fmaxf(fmaxf(accs[0][r], accs[1][r]), fmaxf(accs[2][r], accs[3][r]));
            #pragma unroll
            for (int off = 1; off < 16; off <<= 1) mx = fmaxf(mx, __shfl_xor(mx, off));
            float mnew = fmaxf(mrow[r], mx);
            alpha[r] = __expf(mrow[r] - mnew);
            mrow[r] = mnew;
            float rs = 0.f;
            #pragma unroll
            for (int n = 0; n < 4; n++) {
                float p = __expf(accs[n][r] - mnew);
                accs[n][r] = p;
                rs += p;
            }
            #pragma unroll
            for (int off = 1; off < 16; off <<= 1) rs += __shfl_xor(rs, off);
            lrow[r] = lrow[r] * alpha[r] + rs;
        }
        // P -> LDS (per-wave private tile; same-wave LDS ops are in-order)
        #pragma unroll
        for (int n = 0; n < 4; n++)
            #pragma unroll
            for (int r = 0; r < 4; r++)
                plds[wid][lg * 4 + r][n * 16 + lr] = f2bf(accs[n][r]);
        asm volatile("s_waitcnt lgkmcnt(0)" ::: "memory");
        // rescale O
        #pragma unroll
        for (int dt = 0; dt < 4; dt++)
            #pragma unroll
            for (int r = 0; r < 4; r++)
                acco[dt][r] *= alpha[r];
        // PV
        #pragma unroll
        for (int kt = 0; kt < 2; kt++) {
            short8 pa = *(const short8*)&plds[wid][lr][kt * 32 + lk];
            #pragma unroll
            for (int dt = 0; dt < 4; dt++) {
                const u16* vptr = vt + ((size_t)bh * HD + dt * 16 + lr) * SS + kv0 + kt * 32 + lk;
                short8 vb = *(const short8*)(vptr);
                acco[dt] = __builtin_amdgcn_mfma_f32_16x16x32_bf16(pa, vb, acco[dt], 0, 0, 0);
            }
        }
    }
    // epilogue: divide by row-sum, write (b, s, h*64+d) bf16
    #pragma unroll
    for (int r = 0; r < 4; r++) {
        float inv = 1.f / lrow[r];
        int qg = q0 + lg * 4 + r;
        #pragma unroll
        for (int dt = 0; dt < 4; dt++)
            attnb[((size_t)b_ * SS + qg) * DD + h * HD + dt * 16 + lr] = f2bf(acco[dt][r] * inv);
    }
}

// ---------------- O-proj GEMM + bias + residual -> res (fp32) --------------
__global__ __launch_bounds__(256) void k_gemm_o(
        const u16* __restrict__ attnb, const u16* __restrict__ wot,
        const float* __restrict__ bo, const float* __restrict__ x,
        float* __restrict__ res) {
    int lane = threadIdx.x & 63, wid = threadIdx.x >> 6;
    int wm = wid >> 1, wn = wid & 1;
    int m0 = blockIdx.x * 128 + wm * 64;
    int n0 = blockIdx.y * 128 + wn * 64;
    int lr = lane & 15, lg = lane >> 4, lk = lg * 8;

    f32x4 acc[4][4] = {};
    for (int kk = 0; kk < DD; kk += 32) {
        short8 a[4], b[4];
        #pragma unroll
        for (int i = 0; i < 4; i++)
            a[i] = *(const short8*)(attnb + (size_t)(m0 + i * 16 + lr) * DD + kk + lk);
        #pragma unroll
        for (int j = 0; j < 4; j++)
            b[j] = *(const short8*)(wot + (size_t)(n0 + j * 16 + lr) * DD + kk + lk);
        #pragma unroll
        for (int i = 0; i < 4; i++)
            #pragma unroll
            for (int j = 0; j < 4; j++)
                acc[i][j] = __builtin_amdgcn_mfma_f32_16x16x32_bf16(a[i], b[j], acc[i][j], 0, 0, 0);
    }
    #pragma unroll
    for (int i = 0; i < 4; i++) {
        #pragma unroll
        for (int j = 0; j < 4; j++) {
            int n = n0 + j * 16 + lr;
            #pragma unroll
            for (int r = 0; r < 4; r++) {
                int m = m0 + i * 16 + lg * 4 + r;
                res[(size_t)m * DD + n] = acc[i][j][r] + bo[n] + x[(size_t)m * DD + n];
            }
        }
    }
}

// ---------------- LayerNorm ------------------------------------------------
__global__ __launch_bounds__(256) void k_ln(const float* __restrict__ res,
        const float* __restrict__ gamma, const float* __restrict__ beta,
        float* __restrict__ out) {
    int row = blockIdx.x, tid = threadIdx.x;
    float4 v = ((const float4*)(res + (size_t)row * DD))[tid];
    float s = v.x + v.y + v.z + v.w;
    float ss = v.x * v.x + v.y * v.y + v.z * v.z + v.w * v.w;
    #pragma unroll
    for (int off = 32; off; off >>= 1) { s += __shfl_xor(s, off); ss += __shfl_xor(ss, off); }
    __shared__ float sbuf[8];
    int wid = tid >> 6, lane = tid & 63;
    if (lane == 0) { sbuf[wid] = s; sbuf[4 + wid] = ss; }
    __syncthreads();
    s = sbuf[0] + sbuf[1] + sbuf[2] + sbuf[3];
    ss = sbuf[4] + sbuf[5] + sbuf[6] + sbuf[7];
    float mu = s * (1.f / DD);
    float var = ss * (1.f / DD) - mu * mu;
    float rstd = rsqrtf(var + LN_EPS);
    float4 g = ((const float4*)gamma)[tid];
    float4 be = ((const float4*)beta)[tid];
    float4 o;
    o.x = (v.x - mu) * rstd * g.x + be.x;
    o.y = (v.y - mu) * rstd * g.y + be.y;
    o.z = (v.z - mu) * rstd * g.z + be.z;
    o.w = (v.w - mu) * rstd * g.w + be.w;
    ((float4*)(out + (size_t)row * DD))[tid] = o;
}

// ---------------- launch ----------------------------------------------------
extern "C" void kernel_launch(void* const* d_in, const int* in_sizes, int n_in,
                              void* d_out, int out_size, void* d_ws, size_t ws_size,
                              hipStream_t stream) {
    const float* x        = (const float*)d_in[0];
    const float* cdr_bias = (const float*)d_in[1];
    const float* Wq       = (const float*)d_in[2];
    const float* bq       = (const float*)d_in[3];
    const float* Wk       = (const float*)d_in[4];
    const float* bk       = (const float*)d_in[5];
    const float* Wv       = (const float*)d_in[6];
    const float* bv       = (const float*)d_in[7];
    const float* Wo       = (const float*)d_in[8];
    const float* bo       = (const float*)d_in[9];
    const float* gamma    = (const float*)d_in[10];
    const float* beta     = (const float*)d_in[11];
    const float* cw       = (const float*)d_in[12];

    char* ws = (char*)d_ws;
    const size_t MB = 1048576;
    u16*   xb     = (u16*)(ws + 0);            // 8 MB
    u16*   wqkvt  = (u16*)(ws + 8 * MB);       // 6 MB
    u16*   wot    = (u16*)(ws + 14 * MB);      // 2 MB
    u16*   qb     = (u16*)(ws + 16 * MB);      // 8 MB
    u16*   kb     = (u16*)(ws + 24 * MB);      // 8 MB
    u16*   vtb    = (u16*)(ws + 32 * MB);      // 8 MB
    u16*   attnb  = (u16*)(ws + 40 * MB);      // 8 MB
    float* res    = (float*)(ws + 48 * MB);    // 16 MB
    float* cosb   = (float*)(ws + 64 * MB);    // 0.5 MB
    float* sinb   = (float*)(ws + 64 * MB + 524288);

    k_convert_x  <<<4096, 256, 0, stream>>>(x, xb);
    k_transpose_w<<<dim3(32, 32, 4), dim3(32, 8), 0, stream>>>(Wq, Wk, Wv, Wo, wqkvt, wot);
    k_rope_table <<<512, 256, 0, stream>>>(cosb, sinb);
    k_gemm_qkv   <<<dim3(32, 24), 256, 0, stream>>>(xb, wqkvt, bq, bk, bv, cosb, sinb, qb, kb, vtb);
    k_attn       <<<dim3(32, 32), 256, 0, stream>>>(qb, kb, vtb, cdr_bias, cw, attnb);
    k_gemm_o     <<<dim3(32, 8), 256, 0, stream>>>(attnb, wot, bo, x, res);
    k_ln         <<<4096, 256, 0, stream>>>(res, gamma, beta, (float*)d_out);
}

// Round 2
// 267.809 us; speedup vs baseline: 1.6420x; 1.6420x over previous
//
#include <hip/hip_runtime.h>
#include <hip/hip_bf16.h>
#include <math.h>

#define BB 2
#define SS 2048
#define DD 1024
#define HH 16
#define HD 64
#define MM (BB*SS)          // 4096
#define LN_EPS 1e-5f
#define KVB 64

typedef unsigned short u16;
typedef __attribute__((ext_vector_type(8))) short short8;
typedef __attribute__((ext_vector_type(4))) float f32x4;
typedef __attribute__((ext_vector_type(4))) unsigned short u16x4;

__device__ __forceinline__ u16 f2bf(float f) {
    union { __hip_bfloat16 h; u16 u; } cv;
    cv.h = __float2bfloat16(f);
    return cv.u;
}

// async global->LDS, 16B per lane. LDS dest must be wave-uniform base + lane*16.
__device__ __forceinline__ void gload16(const void* g, void* l) {
    __builtin_amdgcn_global_load_lds(
        (const __attribute__((address_space(1))) void*)g,
        (__attribute__((address_space(3))) void*)l, 16, 0, 0);
}

// ---------------- convert x (fp32 -> bf16) ---------------------------------
__global__ void k_convert_x(const float* __restrict__ x, u16* __restrict__ xb) {
    int i = blockIdx.x * blockDim.x + threadIdx.x;
    float4 v = ((const float4*)x)[i];
    u16x4 o;
    o[0] = f2bf(v.x); o[1] = f2bf(v.y); o[2] = f2bf(v.z); o[3] = f2bf(v.w);
    ((u16x4*)xb)[i] = o;
}

// ---------------- transpose + convert weights ------------------------------
__global__ void k_transpose_w(const float* __restrict__ Wq, const float* __restrict__ Wk,
                              const float* __restrict__ Wv, const float* __restrict__ Wo,
                              u16* __restrict__ wqkvt, u16* __restrict__ wot) {
    __shared__ float t[32][33];
    int z = blockIdx.z;
    const float* W = (z == 0) ? Wq : (z == 1) ? Wk : (z == 2) ? Wv : Wo;
    u16* dst = (z < 3) ? (wqkvt + (size_t)z * DD * DD) : wot;
    int k0 = blockIdx.x * 32, n0 = blockIdx.y * 32;
    #pragma unroll
    for (int r = 0; r < 32; r += 8)
        t[threadIdx.y + r][threadIdx.x] = W[(size_t)(k0 + threadIdx.y + r) * DD + n0 + threadIdx.x];
    __syncthreads();
    #pragma unroll
    for (int r = 0; r < 32; r += 8)
        dst[(size_t)(n0 + threadIdx.y + r) * DD + k0 + threadIdx.x] = f2bf(t[threadIdx.x][threadIdx.y + r]);
}

// ---------------- RoPE tables + pre-scaled cdr bias ------------------------
__global__ void k_rope_table(float* __restrict__ cosb, float* __restrict__ sinb,
                             const float* __restrict__ cdr_bias, const float* __restrict__ cw,
                             float* __restrict__ biasf) {
    int idx = blockIdx.x * blockDim.x + threadIdx.x;    // 0..131071
    if (idx < BB * SS) biasf[idx] = cdr_bias[idx] * cw[0];
    int s = idx >> 6, j = idx & 63;
    double invf = pow(10000.0, -((double)(2 * (j & 31))) / 64.0);
    double ang = (double)s * invf;
    cosb[idx] = (float)cos(ang);
    sinb[idx] = (float)sin(ang);
}

// ---------------- QKV GEMM + RoPE epilogue ---------------------------------
__global__ __launch_bounds__(256) void k_gemm_qkv(
        const u16* __restrict__ xb, const u16* __restrict__ wqkvt,
        const float* __restrict__ bq, const float* __restrict__ bk, const float* __restrict__ bv,
        const float* __restrict__ cosb, const float* __restrict__ sinb,
        u16* __restrict__ q, u16* __restrict__ k, u16* __restrict__ vt) {
    int lane = threadIdx.x & 63, wid = threadIdx.x >> 6;
    int wm = wid >> 1, wn = wid & 1;
    int m0 = blockIdx.x * 128 + wm * 64;
    int n0 = blockIdx.y * 128 + wn * 64;
    int lr = lane & 15, lg = lane >> 4, lk = lg * 8;

    f32x4 acc[4][4] = {};
    for (int kk = 0; kk < DD; kk += 32) {
        short8 a[4], b[4];
        #pragma unroll
        for (int i = 0; i < 4; i++)
            a[i] = *(const short8*)(xb + (size_t)(m0 + i * 16 + lr) * DD + kk + lk);
        #pragma unroll
        for (int j = 0; j < 4; j++)
            b[j] = *(const short8*)(wqkvt + (size_t)(n0 + j * 16 + lr) * DD + kk + lk);
        #pragma unroll
        for (int i = 0; i < 4; i++)
            #pragma unroll
            for (int j = 0; j < 4; j++)
                acc[i][j] = __builtin_amdgcn_mfma_f32_16x16x32_bf16(a[i], b[j], acc[i][j], 0, 0, 0);
    }

    #pragma unroll
    for (int j = 0; j < 4; j++) {
        int n = n0 + j * 16 + lr;
        int w = n >> 10;
        int n1 = n & 1023;
        int h = n1 >> 6, d = n1 & 63;
        float bias = (w == 0) ? bq[n1] : (w == 1) ? bk[n1] : bv[n1];
        #pragma unroll
        for (int i = 0; i < 4; i++) {
            #pragma unroll
            for (int r = 0; r < 4; r++) {
                int m = m0 + i * 16 + lg * 4 + r;
                int b_ = m >> 11, s = m & 2047;
                float val = acc[i][j][r] + bias;
                float part = __shfl_xor(val, 1);
                if (w < 2) {
                    float c = cosb[s * 64 + d], sn = sinb[s * 64 + d];
                    float rot = (d & 1) ? part : -part;
                    val = val * c + rot * sn;
                }
                size_t bh = (size_t)(b_ * HH + h);
                if (w == 0) {
                    q[(bh * SS + s) * HD + d] = f2bf(val * 0.125f);   // fold 1/sqrt(64)
                } else if (w == 1) {
                    k[(bh * SS + s) * HD + d] = f2bf(val);
                } else {
                    vt[(bh * HD + d) * SS + s] = f2bf(val);           // V transposed (d-major)
                }
            }
        }
    }
}

// ---------------- Flash attention (block-coop, swapped QK^T) ----------------
// grid (S/128, B*H), 4 waves/block, 32 q-rows per wave. KV tile = 64 shared via LDS.
// K/V staged with global_load_lds; XOR-swizzle applied on the GLOBAL source
// (LDS dest stays linear), reads use the same XOR -> conflict-free ds_read_b128.
__device__ __forceinline__ void stage64x64(const u16* __restrict__ gbase, size_t rstride,
                                           u16* lds, int tid) {
    #pragma unroll
    for (int i = 0; i < 2; i++) {
        int L = i * 256 + tid;               // 16B chunk index, 0..511
        int row = L >> 3, c = L & 7;
        gload16(gbase + (size_t)row * rstride + (size_t)((c ^ (row & 7)) << 3), lds + L * 8);
    }
}

__global__ __launch_bounds__(256) void k_attn(
        const u16* __restrict__ q, const u16* __restrict__ kkv, const u16* __restrict__ vt,
        const float* __restrict__ biasf, u16* __restrict__ attnb) {
    __shared__ u16 Klds[2][64 * 64];
    __shared__ u16 Vlds[2][64 * 64];
    __shared__ u16 plds[4][32][72];          // per-wave P tile, 144B rows (16B-mult)
    __shared__ float biasl[SS];

    int tid = threadIdx.x;
    int lane = tid & 63, wid = tid >> 6;
    int bh = blockIdx.y, b_ = bh >> 4, h = bh & 15;
    int q0 = blockIdx.x * 128 + wid * 32;
    int lr = lane & 15, lg = lane >> 4;

    // stage bias row (8KB) once
    #pragma unroll
    for (int i = 0; i < 2; i++) {
        int L = i * 256 + tid;
        gload16(biasf + (size_t)b_ * SS + L * 4, (void*)(biasl + L * 4));
    }
    // Q fragments in registers (B-operand: col = q = lr)
    short8 qa[2][2];
    #pragma unroll
    for (int qf = 0; qf < 2; qf++)
        #pragma unroll
        for (int ks = 0; ks < 2; ks++)
            qa[qf][ks] = *(const short8*)(q + ((size_t)bh * SS + q0 + qf * 16 + lr) * HD + ks * 32 + lg * 8);

    stage64x64(kkv + ((size_t)bh * SS) * HD, HD, Klds[0], tid);
    stage64x64(vt + ((size_t)bh * HD) * SS, SS, Vlds[0], tid);
    __syncthreads();

    f32x4 acco[2][4] = {};
    float mrow[2] = {-1e30f, -1e30f};
    float lrow[2] = {0.f, 0.f};

    for (int t = 0; t < SS / KVB; t++) {
        int cur = t & 1;
        if (t + 1 < SS / KVB) {              // prefetch next tile (issue-early)
            int kv1 = (t + 1) * KVB;
            stage64x64(kkv + ((size_t)bh * SS + kv1) * HD, HD, Klds[cur ^ 1], tid);
            stage64x64(vt + ((size_t)bh * HD) * SS + kv1, SS, Vlds[cur ^ 1], tid);
        }
        const u16* Kc = Klds[cur];
        const u16* Vc = Vlds[cur];

        // K fragments (A-operand: row = k) and V^T fragments (B-operand: col = d)
        short8 kf[4][2], vf[4][2];
        #pragma unroll
        for (int n = 0; n < 4; n++) {
            int row = n * 16 + lr;
            #pragma unroll
            for (int ks = 0; ks < 2; ks++)
                kf[n][ks] = *(const short8*)(Kc + row * 64 + (((ks * 4 + lg) ^ (lr & 7)) << 3));
        }
        #pragma unroll
        for (int dt = 0; dt < 4; dt++) {
            int row = dt * 16 + lr;
            #pragma unroll
            for (int kt = 0; kt < 2; kt++)
                vf[dt][kt] = *(const short8*)(Vc + row * 64 + (((kt * 4 + lg) ^ (lr & 7)) << 3));
        }

        #pragma unroll
        for (int qf = 0; qf < 2; qf++) {
            // S^T = K · Q : lane holds S[k = n*16+lg*4+r][q = lr]
            f32x4 s_[4] = {};
            #pragma unroll
            for (int n = 0; n < 4; n++) {
                s_[n] = __builtin_amdgcn_mfma_f32_16x16x32_bf16(kf[n][0], qa[qf][0], s_[n], 0, 0, 0);
                s_[n] = __builtin_amdgcn_mfma_f32_16x16x32_bf16(kf[n][1], qa[qf][1], s_[n], 0, 0, 0);
            }
            // add cdr bias (varies along k) before max
            #pragma unroll
            for (int n = 0; n < 4; n++) {
                float4 b4 = *(const float4*)&biasl[t * KVB + n * 16 + lg * 4];
                s_[n][0] += b4.x; s_[n][1] += b4.y; s_[n][2] += b4.z; s_[n][3] += b4.w;
            }
            // row (q) reduction: local 16 values, then xor over lane-groups {16,32}
            float mx = -1e30f;
            #pragma unroll
            for (int n = 0; n < 4; n++)
                mx = fmaxf(mx, fmaxf(fmaxf(s_[n][0], s_[n][1]), fmaxf(s_[n][2], s_[n][3])));
            mx = fmaxf(mx, __shfl_xor(mx, 16));
            mx = fmaxf(mx, __shfl_xor(mx, 32));
            float mnew = fmaxf(mrow[qf], mx);
            float al = __expf(mrow[qf] - mnew);
            mrow[qf] = mnew;
            float rs = 0.f;
            #pragma unroll
            for (int n = 0; n < 4; n++) {
                #pragma unroll
                for (int r = 0; r < 4; r++) {
                    float p = __expf(s_[n][r] - mnew);
                    s_[n][r] = p;
                    rs += p;
                }
            }
            rs += __shfl_xor(rs, 16);
            rs += __shfl_xor(rs, 32);
            lrow[qf] = lrow[qf] * al + rs;
            // P -> LDS (per-wave private): plds[q][k], 8B packed writes
            #pragma unroll
            for (int n = 0; n < 4; n++) {
                ushort4 pk;
                pk.x = f2bf(s_[n][0]); pk.y = f2bf(s_[n][1]);
                pk.z = f2bf(s_[n][2]); pk.w = f2bf(s_[n][3]);
                *(ushort4*)&plds[wid][qf * 16 + lr][n * 16 + lg * 4] = pk;
            }
            // alpha lives at lanes lr==q; redistribute to acco layout (q = lg*4+r)
            float alr[4];
            #pragma unroll
            for (int r = 0; r < 4; r++) alr[r] = __shfl(al, lg * 4 + r);
            #pragma unroll
            for (int dt = 0; dt < 4; dt++) {
                acco[qf][dt][0] *= alr[0]; acco[qf][dt][1] *= alr[1];
                acco[qf][dt][2] *= alr[2]; acco[qf][dt][3] *= alr[3];
            }
            // PV: O[q][d] += P · V
            #pragma unroll
            for (int kt = 0; kt < 2; kt++) {
                short8 pa = *(const short8*)&plds[wid][qf * 16 + lr][kt * 32 + lg * 8];
                #pragma unroll
                for (int dt = 0; dt < 4; dt++)
                    acco[qf][dt] = __builtin_amdgcn_mfma_f32_16x16x32_bf16(pa, vf[dt][kt], acco[qf][dt], 0, 0, 0);
            }
        }
        __syncthreads();                     // drains global_load_lds (vmcnt) + LDS reads
    }

    // epilogue: divide by row-sum (redistribute l to acco layout), write bf16
    #pragma unroll
    for (int qf = 0; qf < 2; qf++) {
        float linv[4];
        #pragma unroll
        for (int r = 0; r < 4; r++) linv[r] = 1.f / __shfl(lrow[qf], lg * 4 + r);
        #pragma unroll
        for (int dt = 0; dt < 4; dt++)
            #pragma unroll
            for (int r = 0; r < 4; r++)
                attnb[((size_t)b_ * SS + q0 + qf * 16 + lg * 4 + r) * DD + h * HD + dt * 16 + lr] =
                    f2bf(acco[qf][dt][r] * linv[r]);
    }
}

// ---------------- O-proj GEMM + bias + residual -> res (fp32) --------------
__global__ __launch_bounds__(256) void k_gemm_o(
        const u16* __restrict__ attnb, const u16* __restrict__ wot,
        const float* __restrict__ bo, const float* __restrict__ x,
        float* __restrict__ res) {
    int lane = threadIdx.x & 63, wid = threadIdx.x >> 6;
    int wm = wid >> 1, wn = wid & 1;
    int m0 = blockIdx.x * 128 + wm * 64;
    int n0 = blockIdx.y * 128 + wn * 64;
    int lr = lane & 15, lg = lane >> 4, lk = lg * 8;

    f32x4 acc[4][4] = {};
    for (int kk = 0; kk < DD; kk += 32) {
        short8 a[4], b[4];
        #pragma unroll
        for (int i = 0; i < 4; i++)
            a[i] = *(const short8*)(attnb + (size_t)(m0 + i * 16 + lr) * DD + kk + lk);
        #pragma unroll
        for (int j = 0; j < 4; j++)
            b[j] = *(const short8*)(wot + (size_t)(n0 + j * 16 + lr) * DD + kk + lk);
        #pragma unroll
        for (int i = 0; i < 4; i++)
            #pragma unroll
            for (int j = 0; j < 4; j++)
                acc[i][j] = __builtin_amdgcn_mfma_f32_16x16x32_bf16(a[i], b[j], acc[i][j], 0, 0, 0);
    }
    #pragma unroll
    for (int i = 0; i < 4; i++) {
        #pragma unroll
        for (int j = 0; j < 4; j++) {
            int n = n0 + j * 16 + lr;
            #pragma unroll
            for (int r = 0; r < 4; r++) {
                int m = m0 + i * 16 + lg * 4 + r;
                res[(size_t)m * DD + n] = acc[i][j][r] + bo[n] + x[(size_t)m * DD + n];
            }
        }
    }
}

// ---------------- LayerNorm ------------------------------------------------
__global__ __launch_bounds__(256) void k_ln(const float* __restrict__ res,
        const float* __restrict__ gamma, const float* __restrict__ beta,
        float* __restrict__ out) {
    int row = blockIdx.x, tid = threadIdx.x;
    float4 v = ((const float4*)(res + (size_t)row * DD))[tid];
    float s = v.x + v.y + v.z + v.w;
    float ss = v.x * v.x + v.y * v.y + v.z * v.z + v.w * v.w;
    #pragma unroll
    for (int off = 32; off; off >>= 1) { s += __shfl_xor(s, off); ss += __shfl_xor(ss, off); }
    __shared__ float sbuf[8];
    int wid = tid >> 6, lane = tid & 63;
    if (lane == 0) { sbuf[wid] = s; sbuf[4 + wid] = ss; }
    __syncthreads();
    s = sbuf[0] + sbuf[1] + sbuf[2] + sbuf[3];
    ss = sbuf[4] + sbuf[5] + sbuf[6] + sbuf[7];
    float mu = s * (1.f / DD);
    float var = ss * (1.f / DD) - mu * mu;
    float rstd = rsqrtf(var + LN_EPS);
    float4 g = ((const float4*)gamma)[tid];
    float4 be = ((const float4*)beta)[tid];
    float4 o;
    o.x = (v.x - mu) * rstd * g.x + be.x;
    o.y = (v.y - mu) * rstd * g.y + be.y;
    o.z = (v.z - mu) * rstd * g.z + be.z;
    o.w = (v.w - mu) * rstd * g.w + be.w;
    ((float4*)(out + (size_t)row * DD))[tid] = o;
}

// ---------------- launch ----------------------------------------------------
extern "C" void kernel_launch(void* const* d_in, const int* in_sizes, int n_in,
                              void* d_out, int out_size, void* d_ws, size_t ws_size,
                              hipStream_t stream) {
    const float* x        = (const float*)d_in[0];
    const float* cdr_bias = (const float*)d_in[1];
    const float* Wq       = (const float*)d_in[2];
    const float* bq       = (const float*)d_in[3];
    const float* Wk       = (const float*)d_in[4];
    const float* bk       = (const float*)d_in[5];
    const float* Wv       = (const float*)d_in[6];
    const float* bv       = (const float*)d_in[7];
    const float* Wo       = (const float*)d_in[8];
    const float* bo       = (const float*)d_in[9];
    const float* gamma    = (const float*)d_in[10];
    const float* beta     = (const float*)d_in[11];
    const float* cw       = (const float*)d_in[12];

    char* ws = (char*)d_ws;
    const size_t MB = 1048576;
    u16*   xb     = (u16*)(ws + 0);            // 8 MB
    u16*   wqkvt  = (u16*)(ws + 8 * MB);       // 6 MB
    u16*   wot    = (u16*)(ws + 14 * MB);      // 2 MB
    u16*   qb     = (u16*)(ws + 16 * MB);      // 8 MB
    u16*   kb     = (u16*)(ws + 24 * MB);      // 8 MB
    u16*   vtb    = (u16*)(ws + 32 * MB);      // 8 MB
    u16*   attnb  = (u16*)(ws + 40 * MB);      // 8 MB
    float* res    = (float*)(ws + 48 * MB);    // 16 MB
    float* biasf  = (float*)(ws + 48 * MB);    // 16 KB, overlaps res (res written later)
    float* cosb   = (float*)(ws + 64 * MB);    // 0.5 MB
    float* sinb   = (float*)(ws + 64 * MB + 524288);

    k_convert_x  <<<4096, 256, 0, stream>>>(x, xb);
    k_transpose_w<<<dim3(32, 32, 4), dim3(32, 8), 0, stream>>>(Wq, Wk, Wv, Wo, wqkvt, wot);
    k_rope_table <<<512, 256, 0, stream>>>(cosb, sinb, cdr_bias, cw, biasf);
    k_gemm_qkv   <<<dim3(32, 24), 256, 0, stream>>>(xb, wqkvt, bq, bk, bv, cosb, sinb, qb, kb, vtb);
    k_attn       <<<dim3(16, 32), 256, 0, stream>>>(qb, kb, vtb, biasf, attnb);
    k_gemm_o     <<<dim3(32, 8), 256, 0, stream>>>(attnb, wot, bo, x, res);
    k_ln         <<<4096, 256, 0, stream>>>(res, gamma, beta, (float*)d_out);
}

// Round 3
// 193.924 us; speedup vs baseline: 2.2677x; 1.3810x over previous
//
#include <hip/hip_runtime.h>
#include <hip/hip_bf16.h>
#include <math.h>

#define BB 2
#define SS 2048
#define DD 1024
#define HH 16
#define HD 64
#define MM (BB*SS)          // 4096
#define LN_EPS 1e-5f
#define KVB 64

typedef unsigned short u16;
typedef __attribute__((ext_vector_type(8))) short short8;
typedef __attribute__((ext_vector_type(4))) float f32x4;
typedef __attribute__((ext_vector_type(4))) unsigned short u16x4;

__device__ __forceinline__ u16 f2bf(float f) {
    union { __hip_bfloat16 h; u16 u; } cv;
    cv.h = __float2bfloat16(f);
    return cv.u;
}

// async global->LDS, 16B per lane. LDS dest must be wave-uniform base + lane*16.
__device__ __forceinline__ void gload16(const void* g, void* l) {
    __builtin_amdgcn_global_load_lds(
        (const __attribute__((address_space(1))) void*)g,
        (__attribute__((address_space(3))) void*)l, 16, 0, 0);
}

// ---------------- convert x (fp32 -> bf16) ---------------------------------
__global__ void k_convert_x(const float* __restrict__ x, u16* __restrict__ xb) {
    int i = blockIdx.x * blockDim.x + threadIdx.x;
    float4 v = ((const float4*)x)[i];
    u16x4 o;
    o[0] = f2bf(v.x); o[1] = f2bf(v.y); o[2] = f2bf(v.z); o[3] = f2bf(v.w);
    ((u16x4*)xb)[i] = o;
}

// ---------------- transpose + convert weights ------------------------------
__global__ void k_transpose_w(const float* __restrict__ Wq, const float* __restrict__ Wk,
                              const float* __restrict__ Wv, const float* __restrict__ Wo,
                              u16* __restrict__ wqkvt, u16* __restrict__ wot) {
    __shared__ float t[32][33];
    int z = blockIdx.z;
    const float* W = (z == 0) ? Wq : (z == 1) ? Wk : (z == 2) ? Wv : Wo;
    u16* dst = (z < 3) ? (wqkvt + (size_t)z * DD * DD) : wot;
    int k0 = blockIdx.x * 32, n0 = blockIdx.y * 32;
    #pragma unroll
    for (int r = 0; r < 32; r += 8)
        t[threadIdx.y + r][threadIdx.x] = W[(size_t)(k0 + threadIdx.y + r) * DD + n0 + threadIdx.x];
    __syncthreads();
    #pragma unroll
    for (int r = 0; r < 32; r += 8)
        dst[(size_t)(n0 + threadIdx.y + r) * DD + k0 + threadIdx.x] = f2bf(t[threadIdx.x][threadIdx.y + r]);
}

// ---------------- RoPE tables + pre-scaled cdr bias ------------------------
__global__ void k_rope_table(float* __restrict__ cosb, float* __restrict__ sinb,
                             const float* __restrict__ cdr_bias, const float* __restrict__ cw,
                             float* __restrict__ biasf) {
    int idx = blockIdx.x * blockDim.x + threadIdx.x;    // 0..131071
    if (idx < BB * SS) biasf[idx] = cdr_bias[idx] * cw[0];
    int s = idx >> 6, j = idx & 63;
    double invf = pow(10000.0, -((double)(2 * (j & 31))) / 64.0);
    double ang = (double)s * invf;
    cosb[idx] = (float)cos(ang);
    sinb[idx] = (float)sin(ang);
}

// ============================================================================
// m97-structure GEMM core: 128x128 tile, BK=32, LDS-staged via global_load_lds,
// XOR-swizzled 16B chunks (swizzle applied on global source AND ds_read addr;
// LDS dest linear — rule 21). 8 ds_read_b128 + 16 MFMA per wave per K-step.
// A: M x K row-major bf16; Bt: N x K row-major bf16 (both K-contiguous).
// ============================================================================
#define GEMM_TILE_LOOP(A_PTR, B_PTR)                                           \
    f32x4 acc[4][4] = {};                                                      \
    for (int kk = 0; kk < DD; kk += 32) {                                      \
        _Pragma("unroll")                                                      \
        for (int i = 0; i < 2; i++) {                                          \
            int L = i * 256 + tid;                                             \
            int row = L >> 2;                                                  \
            int c = (L & 3) ^ ((row >> 1) & 3);                                \
            gload16(A_PTR + (size_t)(bm + row) * DD + kk + c * 8, Alds + L * 8); \
            gload16(B_PTR + (size_t)(bn + row) * DD + kk + c * 8, Blds + L * 8); \
        }                                                                      \
        __syncthreads();                                                       \
        short8 a[4], b[4];                                                     \
        int rchunk = lg ^ ((lr >> 1) & 3);                                     \
        _Pragma("unroll")                                                      \
        for (int i = 0; i < 4; i++)                                            \
            a[i] = *(const short8*)(Alds + (wm * 64 + i * 16 + lr) * 32 + rchunk * 8); \
        _Pragma("unroll")                                                      \
        for (int j = 0; j < 4; j++)                                            \
            b[j] = *(const short8*)(Blds + (wn * 64 + j * 16 + lr) * 32 + rchunk * 8); \
        _Pragma("unroll")                                                      \
        for (int i = 0; i < 4; i++)                                            \
            _Pragma("unroll")                                                  \
            for (int j = 0; j < 4; j++)                                        \
                acc[i][j] = __builtin_amdgcn_mfma_f32_16x16x32_bf16(a[i], b[j], acc[i][j], 0, 0, 0); \
        __syncthreads();                                                       \
    }

// ---------------- QKV GEMM + RoPE epilogue ---------------------------------
__global__ __launch_bounds__(256) void k_gemm_qkv(
        const u16* __restrict__ xb, const u16* __restrict__ wqkvt,
        const float* __restrict__ bq, const float* __restrict__ bk, const float* __restrict__ bv,
        const float* __restrict__ cosb, const float* __restrict__ sinb,
        u16* __restrict__ q, u16* __restrict__ k, u16* __restrict__ vt) {
    __shared__ u16 Alds[128 * 32];
    __shared__ u16 Blds[128 * 32];
    int tid = threadIdx.x;
    int lane = tid & 63, wid = tid >> 6;
    int wm = wid >> 1, wn = wid & 1;
    int bm = blockIdx.x * 128, bn = blockIdx.y * 128;
    int lr = lane & 15, lg = lane >> 4;

    GEMM_TILE_LOOP(xb, wqkvt)

    int m0 = bm + wm * 64, n0 = bn + wn * 64;
    #pragma unroll
    for (int j = 0; j < 4; j++) {
        int n = n0 + j * 16 + lr;
        int w = n >> 10;
        int n1 = n & 1023;
        int h = n1 >> 6, d = n1 & 63;
        float bias = (w == 0) ? bq[n1] : (w == 1) ? bk[n1] : bv[n1];
        #pragma unroll
        for (int i = 0; i < 4; i++) {
            #pragma unroll
            for (int r = 0; r < 4; r++) {
                int m = m0 + i * 16 + lg * 4 + r;
                int b_ = m >> 11, s = m & 2047;
                float val = acc[i][j][r] + bias;
                float part = __shfl_xor(val, 1);
                if (w < 2) {
                    float c = cosb[s * 64 + d], sn = sinb[s * 64 + d];
                    float rot = (d & 1) ? part : -part;
                    val = val * c + rot * sn;
                }
                size_t bh = (size_t)(b_ * HH + h);
                if (w == 0) {
                    q[(bh * SS + s) * HD + d] = f2bf(val * 0.125f);   // fold 1/sqrt(64)
                } else if (w == 1) {
                    k[(bh * SS + s) * HD + d] = f2bf(val);
                } else {
                    vt[(bh * HD + d) * SS + s] = f2bf(val);           // V transposed (d-major)
                }
            }
        }
    }
}

// ---------------- O-proj GEMM + bias + residual -> res (fp32) --------------
__global__ __launch_bounds__(256) void k_gemm_o(
        const u16* __restrict__ attnb, const u16* __restrict__ wot,
        const float* __restrict__ bo, const float* __restrict__ x,
        float* __restrict__ res) {
    __shared__ u16 Alds[128 * 32];
    __shared__ u16 Blds[128 * 32];
    int tid = threadIdx.x;
    int lane = tid & 63, wid = tid >> 6;
    int wm = wid >> 1, wn = wid & 1;
    int bm = blockIdx.x * 128, bn = blockIdx.y * 128;
    int lr = lane & 15, lg = lane >> 4;

    GEMM_TILE_LOOP(attnb, wot)

    int m0 = bm + wm * 64, n0 = bn + wn * 64;
    #pragma unroll
    for (int i = 0; i < 4; i++) {
        #pragma unroll
        for (int j = 0; j < 4; j++) {
            int n = n0 + j * 16 + lr;
            #pragma unroll
            for (int r = 0; r < 4; r++) {
                int m = m0 + i * 16 + lg * 4 + r;
                res[(size_t)m * DD + n] = acc[i][j][r] + bo[n] + x[(size_t)m * DD + n];
            }
        }
    }
}

// ---------------- Flash attention (block-coop, swapped QK^T) ----------------
__device__ __forceinline__ void stage64x64(const u16* __restrict__ gbase, size_t rstride,
                                           u16* lds, int tid) {
    #pragma unroll
    for (int i = 0; i < 2; i++) {
        int L = i * 256 + tid;               // 16B chunk index, 0..511
        int row = L >> 3, c = L & 7;
        gload16(gbase + (size_t)row * rstride + (size_t)((c ^ (row & 7)) << 3), lds + L * 8);
    }
}

__global__ __launch_bounds__(256) void k_attn(
        const u16* __restrict__ q, const u16* __restrict__ kkv, const u16* __restrict__ vt,
        const float* __restrict__ biasf, u16* __restrict__ attnb) {
    __shared__ u16 Klds[2][64 * 64];
    __shared__ u16 Vlds[2][64 * 64];
    __shared__ u16 plds[4][32][72];          // per-wave P tile, 144B rows (16B-mult)
    __shared__ float biasl[SS];

    int tid = threadIdx.x;
    int lane = tid & 63, wid = tid >> 6;
    int bh = blockIdx.y, b_ = bh >> 4, h = bh & 15;
    int q0 = blockIdx.x * 128 + wid * 32;
    int lr = lane & 15, lg = lane >> 4;

    // stage bias row (8KB) once
    #pragma unroll
    for (int i = 0; i < 2; i++) {
        int L = i * 256 + tid;
        gload16(biasf + (size_t)b_ * SS + L * 4, (void*)(biasl + L * 4));
    }
    // Q fragments in registers (B-operand: col = q = lr)
    short8 qa[2][2];
    #pragma unroll
    for (int qf = 0; qf < 2; qf++)
        #pragma unroll
        for (int ks = 0; ks < 2; ks++)
            qa[qf][ks] = *(const short8*)(q + ((size_t)bh * SS + q0 + qf * 16 + lr) * HD + ks * 32 + lg * 8);

    stage64x64(kkv + ((size_t)bh * SS) * HD, HD, Klds[0], tid);
    stage64x64(vt + ((size_t)bh * HD) * SS, SS, Vlds[0], tid);
    __syncthreads();

    f32x4 acco[2][4] = {};
    float mrow[2] = {-1e30f, -1e30f};
    float lrow[2] = {0.f, 0.f};

    for (int t = 0; t < SS / KVB; t++) {
        int cur = t & 1;
        if (t + 1 < SS / KVB) {              // prefetch next tile (issue-early)
            int kv1 = (t + 1) * KVB;
            stage64x64(kkv + ((size_t)bh * SS + kv1) * HD, HD, Klds[cur ^ 1], tid);
            stage64x64(vt + ((size_t)bh * HD) * SS + kv1, SS, Vlds[cur ^ 1], tid);
        }
        const u16* Kc = Klds[cur];
        const u16* Vc = Vlds[cur];

        // K fragments (A-operand: row = k) and V^T fragments (B-operand: col = d)
        short8 kf[4][2], vf[4][2];
        #pragma unroll
        for (int n = 0; n < 4; n++) {
            int row = n * 16 + lr;
            #pragma unroll
            for (int ks = 0; ks < 2; ks++)
                kf[n][ks] = *(const short8*)(Kc + row * 64 + (((ks * 4 + lg) ^ (lr & 7)) << 3));
        }
        #pragma unroll
        for (int dt = 0; dt < 4; dt++) {
            int row = dt * 16 + lr;
            #pragma unroll
            for (int kt = 0; kt < 2; kt++)
                vf[dt][kt] = *(const short8*)(Vc + row * 64 + (((kt * 4 + lg) ^ (lr & 7)) << 3));
        }

        #pragma unroll
        for (int qf = 0; qf < 2; qf++) {
            // S^T = K · Q : lane holds S[k = n*16+lg*4+r][q = lr]
            f32x4 s_[4] = {};
            #pragma unroll
            for (int n = 0; n < 4; n++) {
                s_[n] = __builtin_amdgcn_mfma_f32_16x16x32_bf16(kf[n][0], qa[qf][0], s_[n], 0, 0, 0);
                s_[n] = __builtin_amdgcn_mfma_f32_16x16x32_bf16(kf[n][1], qa[qf][1], s_[n], 0, 0, 0);
            }
            // add cdr bias (varies along k) before max
            #pragma unroll
            for (int n = 0; n < 4; n++) {
                float4 b4 = *(const float4*)&biasl[t * KVB + n * 16 + lg * 4];
                s_[n][0] += b4.x; s_[n][1] += b4.y; s_[n][2] += b4.z; s_[n][3] += b4.w;
            }
            // row (q) reduction: local 16 values, then xor over lane-groups {16,32}
            float mx = -1e30f;
            #pragma unroll
            for (int n = 0; n < 4; n++)
                mx = fmaxf(mx, fmaxf(fmaxf(s_[n][0], s_[n][1]), fmaxf(s_[n][2], s_[n][3])));
            mx = fmaxf(mx, __shfl_xor(mx, 16));
            mx = fmaxf(mx, __shfl_xor(mx, 32));
            float mnew = fmaxf(mrow[qf], mx);
            float al = __expf(mrow[qf] - mnew);
            mrow[qf] = mnew;
            float rs = 0.f;
            #pragma unroll
            for (int n = 0; n < 4; n++) {
                #pragma unroll
                for (int r = 0; r < 4; r++) {
                    float p = __expf(s_[n][r] - mnew);
                    s_[n][r] = p;
                    rs += p;
                }
            }
            rs += __shfl_xor(rs, 16);
            rs += __shfl_xor(rs, 32);
            lrow[qf] = lrow[qf] * al + rs;
            // P -> LDS (per-wave private): plds[q][k], 8B packed writes
            #pragma unroll
            for (int n = 0; n < 4; n++) {
                ushort4 pk;
                pk.x = f2bf(s_[n][0]); pk.y = f2bf(s_[n][1]);
                pk.z = f2bf(s_[n][2]); pk.w = f2bf(s_[n][3]);
                *(ushort4*)&plds[wid][qf * 16 + lr][n * 16 + lg * 4] = pk;
            }
            // alpha lives at lanes lr==q; redistribute to acco layout (q = lg*4+r)
            float alr[4];
            #pragma unroll
            for (int r = 0; r < 4; r++) alr[r] = __shfl(al, lg * 4 + r);
            #pragma unroll
            for (int dt = 0; dt < 4; dt++) {
                acco[qf][dt][0] *= alr[0]; acco[qf][dt][1] *= alr[1];
                acco[qf][dt][2] *= alr[2]; acco[qf][dt][3] *= alr[3];
            }
            // PV: O[q][d] += P · V
            #pragma unroll
            for (int kt = 0; kt < 2; kt++) {
                short8 pa = *(const short8*)&plds[wid][qf * 16 + lr][kt * 32 + lg * 8];
                #pragma unroll
                for (int dt = 0; dt < 4; dt++)
                    acco[qf][dt] = __builtin_amdgcn_mfma_f32_16x16x32_bf16(pa, vf[dt][kt], acco[qf][dt], 0, 0, 0);
            }
        }
        __syncthreads();                     // drains global_load_lds (vmcnt) + LDS reads
    }

    // epilogue: divide by row-sum (redistribute l to acco layout), write bf16
    #pragma unroll
    for (int qf = 0; qf < 2; qf++) {
        float linv[4];
        #pragma unroll
        for (int r = 0; r < 4; r++) linv[r] = 1.f / __shfl(lrow[qf], lg * 4 + r);
        #pragma unroll
        for (int dt = 0; dt < 4; dt++)
            #pragma unroll
            for (int r = 0; r < 4; r++)
                attnb[((size_t)b_ * SS + q0 + qf * 16 + lg * 4 + r) * DD + h * HD + dt * 16 + lr] =
                    f2bf(acco[qf][dt][r] * linv[r]);
    }
}

// ---------------- LayerNorm ------------------------------------------------
__global__ __launch_bounds__(256) void k_ln(const float* __restrict__ res,
        const float* __restrict__ gamma, const float* __restrict__ beta,
        float* __restrict__ out) {
    int row = blockIdx.x, tid = threadIdx.x;
    float4 v = ((const float4*)(res + (size_t)row * DD))[tid];
    float s = v.x + v.y + v.z + v.w;
    float ss = v.x * v.x + v.y * v.y + v.z * v.z + v.w * v.w;
    #pragma unroll
    for (int off = 32; off; off >>= 1) { s += __shfl_xor(s, off); ss += __shfl_xor(ss, off); }
    __shared__ float sbuf[8];
    int wid = tid >> 6, lane = tid & 63;
    if (lane == 0) { sbuf[wid] = s; sbuf[4 + wid] = ss; }
    __syncthreads();
    s = sbuf[0] + sbuf[1] + sbuf[2] + sbuf[3];
    ss = sbuf[4] + sbuf[5] + sbuf[6] + sbuf[7];
    float mu = s * (1.f / DD);
    float var = ss * (1.f / DD) - mu * mu;
    float rstd = rsqrtf(var + LN_EPS);
    float4 g = ((const float4*)gamma)[tid];
    float4 be = ((const float4*)beta)[tid];
    float4 o;
    o.x = (v.x - mu) * rstd * g.x + be.x;
    o.y = (v.y - mu) * rstd * g.y + be.y;
    o.z = (v.z - mu) * rstd * g.z + be.z;
    o.w = (v.w - mu) * rstd * g.w + be.w;
    ((float4*)(out + (size_t)row * DD))[tid] = o;
}

// ---------------- launch ----------------------------------------------------
extern "C" void kernel_launch(void* const* d_in, const int* in_sizes, int n_in,
                              void* d_out, int out_size, void* d_ws, size_t ws_size,
                              hipStream_t stream) {
    const float* x        = (const float*)d_in[0];
    const float* cdr_bias = (const float*)d_in[1];
    const float* Wq       = (const float*)d_in[2];
    const float* bq       = (const float*)d_in[3];
    const float* Wk       = (const float*)d_in[4];
    const float* bk       = (const float*)d_in[5];
    const float* Wv       = (const float*)d_in[6];
    const float* bv       = (const float*)d_in[7];
    const float* Wo       = (const float*)d_in[8];
    const float* bo       = (const float*)d_in[9];
    const float* gamma    = (const float*)d_in[10];
    const float* beta     = (const float*)d_in[11];
    const float* cw       = (const float*)d_in[12];

    char* ws = (char*)d_ws;
    const size_t MB = 1048576;
    u16*   xb     = (u16*)(ws + 0);            // 8 MB
    u16*   wqkvt  = (u16*)(ws + 8 * MB);       // 6 MB
    u16*   wot    = (u16*)(ws + 14 * MB);      // 2 MB
    u16*   qb     = (u16*)(ws + 16 * MB);      // 8 MB
    u16*   kb     = (u16*)(ws + 24 * MB);      // 8 MB
    u16*   vtb    = (u16*)(ws + 32 * MB);      // 8 MB
    u16*   attnb  = (u16*)(ws + 40 * MB);      // 8 MB
    float* res    = (float*)(ws + 48 * MB);    // 16 MB
    float* biasf  = (float*)(ws + 48 * MB);    // 16 KB, overlaps res (res written later)
    float* cosb   = (float*)(ws + 64 * MB);    // 0.5 MB
    float* sinb   = (float*)(ws + 64 * MB + 524288);

    k_convert_x  <<<4096, 256, 0, stream>>>(x, xb);
    k_transpose_w<<<dim3(32, 32, 4), dim3(32, 8), 0, stream>>>(Wq, Wk, Wv, Wo, wqkvt, wot);
    k_rope_table <<<512, 256, 0, stream>>>(cosb, sinb, cdr_bias, cw, biasf);
    k_gemm_qkv   <<<dim3(32, 24), 256, 0, stream>>>(xb, wqkvt, bq, bk, bv, cosb, sinb, qb, kb, vtb);
    k_attn       <<<dim3(16, 32), 256, 0, stream>>>(qb, kb, vtb, biasf, attnb);
    k_gemm_o     <<<dim3(32, 8), 256, 0, stream>>>(attnb, wot, bo, x, res);
    k_ln         <<<4096, 256, 0, stream>>>(res, gamma, beta, (float*)d_out);
}

// Round 4
// 168.753 us; speedup vs baseline: 2.6059x; 1.1492x over previous
//
#include <hip/hip_runtime.h>
#include <hip/hip_bf16.h>
#include <math.h>

#define BB 2
#define SS 2048
#define DD 1024
#define HH 16
#define HD 64
#define MM (BB*SS)          // 4096
#define LN_EPS 1e-5f
#define KVB 64
#define LOG2E 1.44269504088896340736f

typedef unsigned short u16;
typedef __attribute__((ext_vector_type(8))) short short8;
typedef __attribute__((ext_vector_type(4))) float f32x4;
typedef __attribute__((ext_vector_type(4))) unsigned short u16x4;

__device__ __forceinline__ u16 f2bf(float f) {
    union { __hip_bfloat16 h; u16 u; } cv;
    cv.h = __float2bfloat16(f);
    return cv.u;
}

// bare v_exp_f32 = 2^x (CDNA VALU is fully interlocked; no trans-hazard nops needed)
__device__ __forceinline__ float exp2_(float x) {
    float r;
    asm("v_exp_f32 %0, %1" : "=v"(r) : "v"(x));
    return r;
}

// async global->LDS, 16B per lane. LDS dest must be wave-uniform base + lane*16.
__device__ __forceinline__ void gload16(const void* g, void* l) {
    __builtin_amdgcn_global_load_lds(
        (const __attribute__((address_space(1))) void*)g,
        (__attribute__((address_space(3))) void*)l, 16, 0, 0);
}

// ---------------- convert x (fp32 -> bf16) ---------------------------------
__global__ void k_convert_x(const float* __restrict__ x, u16* __restrict__ xb) {
    int i = blockIdx.x * blockDim.x + threadIdx.x;
    float4 v = ((const float4*)x)[i];
    u16x4 o;
    o[0] = f2bf(v.x); o[1] = f2bf(v.y); o[2] = f2bf(v.z); o[3] = f2bf(v.w);
    ((u16x4*)xb)[i] = o;
}

// ---------------- transpose + convert weights ------------------------------
__global__ void k_transpose_w(const float* __restrict__ Wq, const float* __restrict__ Wk,
                              const float* __restrict__ Wv, const float* __restrict__ Wo,
                              u16* __restrict__ wqkvt, u16* __restrict__ wot) {
    __shared__ float t[32][33];
    int z = blockIdx.z;
    const float* W = (z == 0) ? Wq : (z == 1) ? Wk : (z == 2) ? Wv : Wo;
    u16* dst = (z < 3) ? (wqkvt + (size_t)z * DD * DD) : wot;
    int k0 = blockIdx.x * 32, n0 = blockIdx.y * 32;
    #pragma unroll
    for (int r = 0; r < 32; r += 8)
        t[threadIdx.y + r][threadIdx.x] = W[(size_t)(k0 + threadIdx.y + r) * DD + n0 + threadIdx.x];
    __syncthreads();
    #pragma unroll
    for (int r = 0; r < 32; r += 8)
        dst[(size_t)(n0 + threadIdx.y + r) * DD + k0 + threadIdx.x] = f2bf(t[threadIdx.x][threadIdx.y + r]);
}

// ---------------- RoPE tables + pre-scaled cdr bias (log2 domain) ----------
__global__ void k_rope_table(float* __restrict__ cosb, float* __restrict__ sinb,
                             const float* __restrict__ cdr_bias, const float* __restrict__ cw,
                             float* __restrict__ biasf) {
    int idx = blockIdx.x * blockDim.x + threadIdx.x;    // 0..131071
    if (idx < BB * SS) biasf[idx] = cdr_bias[idx] * cw[0] * LOG2E;
    int s = idx >> 6, j = idx & 63;
    double invf = pow(10000.0, -((double)(2 * (j & 31))) / 64.0);
    double ang = (double)s * invf;
    cosb[idx] = (float)cos(ang);
    sinb[idx] = (float)sin(ang);
}

// ============================================================================
// m97-structure GEMM core (see R2 notes).
// ============================================================================
#define GEMM_TILE_LOOP(A_PTR, B_PTR)                                           \
    f32x4 acc[4][4] = {};                                                      \
    for (int kk = 0; kk < DD; kk += 32) {                                      \
        _Pragma("unroll")                                                      \
        for (int i = 0; i < 2; i++) {                                          \
            int L = i * 256 + tid;                                             \
            int row = L >> 2;                                                  \
            int c = (L & 3) ^ ((row >> 1) & 3);                                \
            gload16(A_PTR + (size_t)(bm + row) * DD + kk + c * 8, Alds + L * 8); \
            gload16(B_PTR + (size_t)(bn + row) * DD + kk + c * 8, Blds + L * 8); \
        }                                                                      \
        __syncthreads();                                                       \
        short8 a[4], b[4];                                                     \
        int rchunk = lg ^ ((lr >> 1) & 3);                                     \
        _Pragma("unroll")                                                      \
        for (int i = 0; i < 4; i++)                                            \
            a[i] = *(const short8*)(Alds + (wm * 64 + i * 16 + lr) * 32 + rchunk * 8); \
        _Pragma("unroll")                                                      \
        for (int j = 0; j < 4; j++)                                            \
            b[j] = *(const short8*)(Blds + (wn * 64 + j * 16 + lr) * 32 + rchunk * 8); \
        _Pragma("unroll")                                                      \
        for (int i = 0; i < 4; i++)                                            \
            _Pragma("unroll")                                                  \
            for (int j = 0; j < 4; j++)                                        \
                acc[i][j] = __builtin_amdgcn_mfma_f32_16x16x32_bf16(a[i], b[j], acc[i][j], 0, 0, 0); \
        __syncthreads();                                                       \
    }

// ---------------- QKV GEMM + RoPE epilogue ---------------------------------
__global__ __launch_bounds__(256) void k_gemm_qkv(
        const u16* __restrict__ xb, const u16* __restrict__ wqkvt,
        const float* __restrict__ bq, const float* __restrict__ bk, const float* __restrict__ bv,
        const float* __restrict__ cosb, const float* __restrict__ sinb,
        u16* __restrict__ q, u16* __restrict__ k, u16* __restrict__ vt) {
    __shared__ u16 Alds[128 * 32];
    __shared__ u16 Blds[128 * 32];
    int tid = threadIdx.x;
    int lane = tid & 63, wid = tid >> 6;
    int wm = wid >> 1, wn = wid & 1;
    int bm = blockIdx.x * 128, bn = blockIdx.y * 128;
    int lr = lane & 15, lg = lane >> 4;

    GEMM_TILE_LOOP(xb, wqkvt)

    int m0 = bm + wm * 64, n0 = bn + wn * 64;
    #pragma unroll
    for (int j = 0; j < 4; j++) {
        int n = n0 + j * 16 + lr;
        int w = n >> 10;
        int n1 = n & 1023;
        int h = n1 >> 6, d = n1 & 63;
        float bias = (w == 0) ? bq[n1] : (w == 1) ? bk[n1] : bv[n1];
        #pragma unroll
        for (int i = 0; i < 4; i++) {
            #pragma unroll
            for (int r = 0; r < 4; r++) {
                int m = m0 + i * 16 + lg * 4 + r;
                int b_ = m >> 11, s = m & 2047;
                float val = acc[i][j][r] + bias;
                float part = __shfl_xor(val, 1);
                if (w < 2) {
                    float c = cosb[s * 64 + d], sn = sinb[s * 64 + d];
                    float rot = (d & 1) ? part : -part;
                    val = val * c + rot * sn;
                }
                size_t bh = (size_t)(b_ * HH + h);
                if (w == 0) {
                    q[(bh * SS + s) * HD + d] = f2bf(val * (0.125f * LOG2E));  // 1/sqrt(64) * log2e
                } else if (w == 1) {
                    k[(bh * SS + s) * HD + d] = f2bf(val);
                } else {
                    vt[(bh * HD + d) * SS + s] = f2bf(val);           // V transposed (d-major)
                }
            }
        }
    }
}

// ---------------- O-proj GEMM + bias + residual -> res (fp32) --------------
__global__ __launch_bounds__(256) void k_gemm_o(
        const u16* __restrict__ attnb, const u16* __restrict__ wot,
        const float* __restrict__ bo, const float* __restrict__ x,
        float* __restrict__ res) {
    __shared__ u16 Alds[128 * 32];
    __shared__ u16 Blds[128 * 32];
    int tid = threadIdx.x;
    int lane = tid & 63, wid = tid >> 6;
    int wm = wid >> 1, wn = wid & 1;
    int bm = blockIdx.x * 128, bn = blockIdx.y * 128;
    int lr = lane & 15, lg = lane >> 4;

    GEMM_TILE_LOOP(attnb, wot)

    int m0 = bm + wm * 64, n0 = bn + wn * 64;
    #pragma unroll
    for (int i = 0; i < 4; i++) {
        #pragma unroll
        for (int j = 0; j < 4; j++) {
            int n = n0 + j * 16 + lr;
            #pragma unroll
            for (int r = 0; r < 4; r++) {
                int m = m0 + i * 16 + lg * 4 + r;
                res[(size_t)m * DD + n] = acc[i][j][r] + bo[n] + x[(size_t)m * DD + n];
            }
        }
    }
}

// ---------------- Flash attention (8 waves, 16 q-rows/wave, swapped QK^T) ---
// grid (S/128, B*H), 512 threads. KV tile 64 shared via swizzled LDS dbuf.
__device__ __forceinline__ void stage64x64(const u16* __restrict__ gbase, size_t rstride,
                                           u16* lds, int tid) {
    int row = tid >> 3, c = tid & 7;                   // 512 chunks of 16B
    gload16(gbase + (size_t)row * rstride + (size_t)((c ^ (row & 7)) << 3), lds + tid * 8);
}

__global__ __launch_bounds__(512, 4) void k_attn(
        const u16* __restrict__ q, const u16* __restrict__ kkv, const u16* __restrict__ vt,
        const float* __restrict__ biasf, u16* __restrict__ attnb) {
    __shared__ u16 Klds[2][64 * 64];
    __shared__ u16 Vlds[2][64 * 64];
    __shared__ u16 plds[8][16][72];          // per-wave P tile, 144B rows

    int tid = threadIdx.x;
    int lane = tid & 63, wid = tid >> 6;
    int bh = blockIdx.y, b_ = bh >> 4, h = bh & 15;
    int q0 = blockIdx.x * 128 + wid * 16;
    int lr = lane & 15, lg = lane >> 4;

    // Q fragment in registers (B-operand: col = q = lr); log2e pre-folded
    short8 qa[2];
    #pragma unroll
    for (int ks = 0; ks < 2; ks++)
        qa[ks] = *(const short8*)(q + ((size_t)bh * SS + q0 + lr) * HD + ks * 32 + lg * 8);

    stage64x64(kkv + ((size_t)bh * SS) * HD, HD, Klds[0], tid);
    stage64x64(vt + ((size_t)bh * HD) * SS, SS, Vlds[0], tid);
    __syncthreads();

    f32x4 acco[4] = {};
    float mrow = -1e30f, lrow = 0.f;
    const float* bias_b = biasf + (size_t)b_ * SS;

    for (int t = 0; t < SS / KVB; t++) {
        int cur = t & 1;
        if (t + 1 < SS / KVB) {              // prefetch next tile (issue-early)
            int kv1 = (t + 1) * KVB;
            stage64x64(kkv + ((size_t)bh * SS + kv1) * HD, HD, Klds[cur ^ 1], tid);
            stage64x64(vt + ((size_t)bh * HD) * SS + kv1, SS, Vlds[cur ^ 1], tid);
        }
        const u16* Kc = Klds[cur];
        const u16* Vc = Vlds[cur];

        // bias slice (lane-replicated L2 broadcast loads; log2e pre-folded)
        float4 bb[4];
        #pragma unroll
        for (int n = 0; n < 4; n++)
            bb[n] = *(const float4*)(bias_b + t * KVB + n * 16 + lg * 4);

        // K fragments (A-operand: row = k) and V^T fragments (B-operand: col = d)
        short8 kf[4][2], vf[4][2];
        #pragma unroll
        for (int n = 0; n < 4; n++) {
            int row = n * 16 + lr;
            #pragma unroll
            for (int ks = 0; ks < 2; ks++)
                kf[n][ks] = *(const short8*)(Kc + row * 64 + (((ks * 4 + lg) ^ (lr & 7)) << 3));
        }
        #pragma unroll
        for (int dt = 0; dt < 4; dt++) {
            int row = dt * 16 + lr;
            #pragma unroll
            for (int kt = 0; kt < 2; kt++)
                vf[dt][kt] = *(const short8*)(Vc + row * 64 + (((kt * 4 + lg) ^ (lr & 7)) << 3));
        }

        // S^T = K · Q : lane holds S[k = n*16+lg*4+r][q = lr]   (log2 domain)
        f32x4 s_[4] = {};
        __builtin_amdgcn_s_setprio(1);
        #pragma unroll
        for (int n = 0; n < 4; n++) {
            s_[n] = __builtin_amdgcn_mfma_f32_16x16x32_bf16(kf[n][0], qa[0], s_[n], 0, 0, 0);
            s_[n] = __builtin_amdgcn_mfma_f32_16x16x32_bf16(kf[n][1], qa[1], s_[n], 0, 0, 0);
        }
        __builtin_amdgcn_s_setprio(0);
        #pragma unroll
        for (int n = 0; n < 4; n++) {
            s_[n][0] += bb[n].x; s_[n][1] += bb[n].y; s_[n][2] += bb[n].z; s_[n][3] += bb[n].w;
        }
        // row (q) max: local 16 values, then xor over lane-groups {16,32}
        float mx = -1e30f;
        #pragma unroll
        for (int n = 0; n < 4; n++)
            mx = fmaxf(mx, fmaxf(fmaxf(s_[n][0], s_[n][1]), fmaxf(s_[n][2], s_[n][3])));
        mx = fmaxf(mx, __shfl_xor(mx, 16));
        mx = fmaxf(mx, __shfl_xor(mx, 32));
        // defer-max: skip rescale when no row grew its max by > 8 (p <= 256)
        bool grow = !__all(mx <= mrow + 8.f);
        float mnew = grow ? fmaxf(mrow, mx) : mrow;
        float rs = 0.f;
        #pragma unroll
        for (int n = 0; n < 4; n++) {
            #pragma unroll
            for (int r = 0; r < 4; r++) {
                float p = exp2_(s_[n][r] - mnew);
                s_[n][r] = p;
                rs += p;
            }
        }
        rs += __shfl_xor(rs, 16);
        rs += __shfl_xor(rs, 32);
        if (grow) {
            float al = exp2_(mrow - mnew);
            lrow = lrow * al + rs;
            mrow = mnew;
            float alr[4];
            #pragma unroll
            for (int r = 0; r < 4; r++) alr[r] = __shfl(al, lg * 4 + r);
            #pragma unroll
            for (int dt = 0; dt < 4; dt++) {
                acco[dt][0] *= alr[0]; acco[dt][1] *= alr[1];
                acco[dt][2] *= alr[2]; acco[dt][3] *= alr[3];
            }
        } else {
            lrow += rs;
        }
        // P -> LDS (per-wave private): plds[q][k], 8B packed writes
        #pragma unroll
        for (int n = 0; n < 4; n++) {
            ushort4 pk;
            pk.x = f2bf(s_[n][0]); pk.y = f2bf(s_[n][1]);
            pk.z = f2bf(s_[n][2]); pk.w = f2bf(s_[n][3]);
            *(ushort4*)&plds[wid][lr][n * 16 + lg * 4] = pk;
        }
        asm volatile("s_waitcnt lgkmcnt(0)" ::: "memory");
        // PV: O[q][d] += P · V
        __builtin_amdgcn_s_setprio(1);
        #pragma unroll
        for (int kt = 0; kt < 2; kt++) {
            short8 pa = *(const short8*)&plds[wid][lr][kt * 32 + lg * 8];
            #pragma unroll
            for (int dt = 0; dt < 4; dt++)
                acco[dt] = __builtin_amdgcn_mfma_f32_16x16x32_bf16(pa, vf[dt][kt], acco[dt], 0, 0, 0);
        }
        __builtin_amdgcn_s_setprio(0);
        __syncthreads();                     // drains global_load_lds + LDS reads
    }

    // epilogue: divide by row-sum (redistribute l to acco layout), write bf16
    float linv[4];
    #pragma unroll
    for (int r = 0; r < 4; r++) linv[r] = 1.f / __shfl(lrow, lg * 4 + r);
    #pragma unroll
    for (int dt = 0; dt < 4; dt++)
        #pragma unroll
        for (int r = 0; r < 4; r++)
            attnb[((size_t)b_ * SS + q0 + lg * 4 + r) * DD + h * HD + dt * 16 + lr] =
                f2bf(acco[dt][r] * linv[r]);
}

// ---------------- LayerNorm ------------------------------------------------
__global__ __launch_bounds__(256) void k_ln(const float* __restrict__ res,
        const float* __restrict__ gamma, const float* __restrict__ beta,
        float* __restrict__ out) {
    int row = blockIdx.x, tid = threadIdx.x;
    float4 v = ((const float4*)(res + (size_t)row * DD))[tid];
    float s = v.x + v.y + v.z + v.w;
    float ss = v.x * v.x + v.y * v.y + v.z * v.z + v.w * v.w;
    #pragma unroll
    for (int off = 32; off; off >>= 1) { s += __shfl_xor(s, off); ss += __shfl_xor(ss, off); }
    __shared__ float sbuf[8];
    int wid = tid >> 6, lane = tid & 63;
    if (lane == 0) { sbuf[wid] = s; sbuf[4 + wid] = ss; }
    __syncthreads();
    s = sbuf[0] + sbuf[1] + sbuf[2] + sbuf[3];
    ss = sbuf[4] + sbuf[5] + sbuf[6] + sbuf[7];
    float mu = s * (1.f / DD);
    float var = ss * (1.f / DD) - mu * mu;
    float rstd = rsqrtf(var + LN_EPS);
    float4 g = ((const float4*)gamma)[tid];
    float4 be = ((const float4*)beta)[tid];
    float4 o;
    o.x = (v.x - mu) * rstd * g.x + be.x;
    o.y = (v.y - mu) * rstd * g.y + be.y;
    o.z = (v.z - mu) * rstd * g.z + be.z;
    o.w = (v.w - mu) * rstd * g.w + be.w;
    ((float4*)(out + (size_t)row * DD))[tid] = o;
}

// ---------------- launch ----------------------------------------------------
extern "C" void kernel_launch(void* const* d_in, const int* in_sizes, int n_in,
                              void* d_out, int out_size, void* d_ws, size_t ws_size,
                              hipStream_t stream) {
    const float* x        = (const float*)d_in[0];
    const float* cdr_bias = (const float*)d_in[1];
    const float* Wq       = (const float*)d_in[2];
    const float* bq       = (const float*)d_in[3];
    const float* Wk       = (const float*)d_in[4];
    const float* bk       = (const float*)d_in[5];
    const float* Wv       = (const float*)d_in[6];
    const float* bv       = (const float*)d_in[7];
    const float* Wo       = (const float*)d_in[8];
    const float* bo       = (const float*)d_in[9];
    const float* gamma    = (const float*)d_in[10];
    const float* beta     = (const float*)d_in[11];
    const float* cw       = (const float*)d_in[12];

    char* ws = (char*)d_ws;
    const size_t MB = 1048576;
    u16*   xb     = (u16*)(ws + 0);            // 8 MB
    u16*   wqkvt  = (u16*)(ws + 8 * MB);       // 6 MB
    u16*   wot    = (u16*)(ws + 14 * MB);      // 2 MB
    u16*   qb     = (u16*)(ws + 16 * MB);      // 8 MB
    u16*   kb     = (u16*)(ws + 24 * MB);      // 8 MB
    u16*   vtb    = (u16*)(ws + 32 * MB);      // 8 MB
    u16*   attnb  = (u16*)(ws + 40 * MB);      // 8 MB
    float* res    = (float*)(ws + 48 * MB);    // 16 MB
    float* biasf  = (float*)(ws + 48 * MB);    // 16 KB, overlaps res (res written later)
    float* cosb   = (float*)(ws + 64 * MB);    // 0.5 MB
    float* sinb   = (float*)(ws + 64 * MB + 524288);

    k_convert_x  <<<4096, 256, 0, stream>>>(x, xb);
    k_transpose_w<<<dim3(32, 32, 4), dim3(32, 8), 0, stream>>>(Wq, Wk, Wv, Wo, wqkvt, wot);
    k_rope_table <<<512, 256, 0, stream>>>(cosb, sinb, cdr_bias, cw, biasf);
    k_gemm_qkv   <<<dim3(32, 24), 256, 0, stream>>>(xb, wqkvt, bq, bk, bv, cosb, sinb, qb, kb, vtb);
    k_attn       <<<dim3(16, 32), 512, 0, stream>>>(qb, kb, vtb, biasf, attnb);
    k_gemm_o     <<<dim3(32, 8), 256, 0, stream>>>(attnb, wot, bo, x, res);
    k_ln         <<<4096, 256, 0, stream>>>(res, gamma, beta, (float*)d_out);
}